// Round 10
// baseline (94.655 us; speedup 1.0000x reference)
//
#include <hip/hip_runtime.h>

#define HH 512
#define WW 512
#define RR 5
#define KS 11
#define EPS_F 1e-5f
#define NLOG2E 1.44269504088896340736f
#define TW 64                 // output tile width
#define TH 4                  // output tile height
#define BY 5                  // 320 threads = 5 waves; pass V in one pass
#define SW (TW + 2 * RR)      // 74: strip width (x-halo)
#define SH (TH + 2 * RR)      // 14: halo tile height
#define NHALO (SH * SW)       // 1036 halo pixels
#define NSTRIP (SW * TH)      // 296 strip pixels <= 320 threads

typedef float f2 __attribute__((ext_vector_type(2)));
__device__ __forceinline__ f2 fma2(f2 a, f2 b, f2 c) { return __builtin_elementwise_fma(a, b, c); }

// R10 = R9 + interleaved {img0,img1,img2,t} float4 halo tile in LDS.
// R9 post-mortem: pass-V row body was ~40% accum math (now packed), ~60% load
// machinery (3 global loads x addr VALU + ry clamp + TCP issue, re-done 11x
// per strip column). Staging the halo ONCE in phase 1 turns each pass-V row
// into a single const-offset ds_read_b128 (16B stride = free 2-way aliasing).
// Global loads/block: 9768 -> 4144, all row-contiguous.
// Cost: LDS 32.5 -> 45 KB (3 blocks/CU instead of 4) — issue-slot win should
// dominate at this ILP.
// Algorithm (R7): k(i,j) = t_n^{i^2} * t_n^{j^2}; masked t=0 kills every
// OOB tap: classes a>0 always have exponent>0, and the a=0 class is only
// consumed at the center column (always in-bounds).
// Codegen rules (R1-R6): scalar/constexpr-indexed accumulators, straight-line
// unrolls, no guarded multi-output inner loops (those spilled to VGPR=256).
__global__ __launch_bounds__(320) void gauss_psf_kernel(const float* __restrict__ image,
                                                        const float* __restrict__ psf,
                                                        float* __restrict__ out) {
    __shared__ float4 ht[NHALO];        // {i0,i1,i2,t} halo tile, 16.6 KB
    __shared__ float4 cp[6 * NSTRIP];   // class planes (ch0,ch1,ch2,w), 28.4 KB

    const int tx  = threadIdx.x;            // 0..63
    const int ty  = threadIdx.y;            // 0..4
    const int tid = ty * 64 + tx;           // 0..319
    const int bx0 = blockIdx.x * TW;
    const int by0 = blockIdx.y * TH;
    const int b   = blockIdx.z;

    const float* pw   = psf + (size_t)b * HH * WW;
    const float* img0 = image + (size_t)b * 3 * HH * WW;
    const float* img1 = img0 + HH * WW;
    const float* img2 = img0 + 2 * HH * WW;

    // ---- Phase 1: interleaved halo tile (1036 px, 4 passes of 320) ----
#pragma unroll
    for (int base = 0; base < NHALO; base += 320) {
        const int idx = base + tid;
        if (idx < NHALO) {
            const int row = idx / SW, col = idx - row * SW;
            const int gy = by0 - RR + row, gx = bx0 - RR + col;
            const bool in = ((unsigned)gy < (unsigned)HH) && ((unsigned)gx < (unsigned)WW);
            const int cy = gy < 0 ? 0 : (gy > HH - 1 ? HH - 1 : gy);
            const int cx = gx < 0 ? 0 : (gx > WW - 1 ? WW - 1 : gx);
            const int gi = cy * WW + cx;
            const float w = pw[gi];
            const float a = -NLOG2E * __builtin_amdgcn_rcpf(fmaf(2.0f * w, w, EPS_F));
            const float t = in ? __builtin_amdgcn_exp2f(a) : 0.0f;
            ht[idx] = make_float4(img0[gi], img1[gi], img2[gi], t);
        }
    }
    __syncthreads();

    // ---- Pass V: 296 strip pixels, one per thread ----
    if (tid < NSTRIP) {
        const int ly = tid / SW;            // 0..3
        const int lx = tid - ly * SW;       // 0..73

        f2 a0p[3], a1p[3], a2p[3], awp[3];  // class-pair accumulators
#pragma unroll
        for (int p = 0; p < 3; ++p) {
            a0p[p] = (f2)0.0f; a1p[p] = (f2)0.0f; a2p[p] = (f2)0.0f; awp[p] = (f2)0.0f;
        }

#pragma unroll
        for (int r = 0; r < KS; ++r) {
            const float4 v = ht[(ly + r) * SW + lx];           // ds_read_b128, const off
            const float t = v.w;

            // powers t^{1,4,9,16,25} (7 scalar muls)
            const float t2 = t * t, t4 = t2 * t2, t8 = t4 * t4;
            const float t9 = t8 * t, t16 = t8 * t8, t25 = t16 * t9;

            const int ii = (r - RR) * (r - RR);                // constexpr after unroll
            const float u = ii == 0 ? 1.0f : ii == 1 ? t : ii == 4 ? t4
                          : ii == 9 ? t9 : ii == 16 ? t16 : t25;   // t^(i^2)

            const f2 u2  = {u, u};
            const f2 f01 = u2 * (f2){1.0f, t};                 // t^(i^2+{0,1})
            const f2 f23 = u2 * (f2){t4, t9};                  // t^(i^2+{4,9})
            const f2 f45 = u2 * (f2){t16, t25};                // t^(i^2+{16,25})

            const f2 i0v = {v.x, v.x}, i1v = {v.y, v.y}, i2v = {v.z, v.z};
            a0p[0] = fma2(i0v, f01, a0p[0]);
            a0p[1] = fma2(i0v, f23, a0p[1]);
            a0p[2] = fma2(i0v, f45, a0p[2]);
            a1p[0] = fma2(i1v, f01, a1p[0]);
            a1p[1] = fma2(i1v, f23, a1p[1]);
            a1p[2] = fma2(i1v, f45, a1p[2]);
            a2p[0] = fma2(i2v, f01, a2p[0]);
            a2p[1] = fma2(i2v, f23, a2p[1]);
            a2p[2] = fma2(i2v, f45, a2p[2]);
            awp[0] += f01;
            awp[1] += f23;
            awp[2] += f45;
        }

#pragma unroll
        for (int p = 0; p < 3; ++p) {                          // 6 x ds_write_b128
            cp[(2 * p) * NSTRIP + tid]     = make_float4(a0p[p].x, a1p[p].x, a2p[p].x, awp[p].x);
            cp[(2 * p + 1) * NSTRIP + tid] = make_float4(a0p[p].y, a1p[p].y, a2p[p].y, awp[p].y);
        }
    }
    __syncthreads();

    // ---- Pass H: 256 output pixels (waves 0-3); wave 4 exits uniformly ----
    if (tid < TW * TH) {
        const int hx = tid & 63, hy = tid >> 6;
        const int hb = hy * SW + hx;        // strip index of (y, x-RR+j) at j=0
        f2 s01 = (f2)0.0f, s2w = (f2)0.0f;
#pragma unroll
        for (int j = 0; j < KS; ++j) {
            const int jj = (j - RR) * (j - RR);                // constexpr
            const int ai = jj == 0 ? 0 : jj == 1 ? 1 : jj == 4 ? 2
                         : jj == 9 ? 3 : jj == 16 ? 4 : 5;
            const float4 v = cp[ai * NSTRIP + hb + j];         // ds_read_b128
            s01 += (f2){v.x, v.y};                             // pk_add
            s2w += (f2){v.z, v.w};
        }

        const float sw = s2w.y;                                // >= 1 (center tap)
        float inv = __builtin_amdgcn_rcpf(sw);
        inv = inv * (2.0f - sw * inv);                         // Newton: ~1e-7 rel
        const int x = bx0 + hx, y = by0 + hy;
        const int oi = y * WW + x;
        float* outb = out + (size_t)b * 3 * HH * WW;
        outb[oi]               = s01.x * inv;
        outb[HH * WW + oi]     = s01.y * inv;
        outb[2 * HH * WW + oi] = s2w.x * inv;
    }
}

extern "C" void kernel_launch(void* const* d_in, const int* in_sizes, int n_in,
                              void* d_out, int out_size, void* d_ws, size_t ws_size,
                              hipStream_t stream) {
    const float* image = (const float*)d_in[0];
    const float* psf   = (const float*)d_in[1];
    float* out = (float*)d_out;

    dim3 block(TW, BY, 1);                 // 320 threads = 5 waves
    dim3 grid(WW / TW, HH / TH, 4);        // 8 x 128 x 4 = 4096 blocks
    gauss_psf_kernel<<<grid, block, 0, stream>>>(image, psf, out);
}

// Round 11
// 88.021 us; speedup vs baseline: 1.0754x; 1.0754x over previous
//
#include <hip/hip_runtime.h>

#define HH 512
#define WW 512
#define RR 5
#define KS 11
#define EPS_F 1e-5f
#define NLOG2E 1.44269504088896340736f
#define TW 22                 // output tile width
#define TH 2                  // output tile height
#define SW 32                 // strip width = TW + 2*RR (power of 2!)
#define SH 12                 // halo height = TH + 2*RR
#define NHALO (SH * SW)       // 384 = 6 * 64 exactly
#define NSTRIP (SW * TH)      // 64 = one full wave
#define NOUT (TW * TH)        // 44 outputs per block

typedef float f2 __attribute__((ext_vector_type(2)));
__device__ __forceinline__ f2 fma2(f2 a, f2 b, f2 c) { return __builtin_elementwise_fma(a, b, c); }

// R11: single-WAVE blocks (64 thr), 22x2 outputs. R10's post-mortem showed
// R9's pipes (VALU 8 / LDS 8.7 / TCP 5 us per CU) sum to ~10 us overlapped
// but the kernel runs ~30: two barriers x 5-wave convoys + phase-skewed pipe
// mixes serialize. One wave per block removes convoys entirely (s_barrier
// with one wave is free); 16-20 INDEPENDENT waves/CU overlap the phases.
// Accepted cost: halo redundancy (exp x2.2, img loads +30%) — small vs the
// 3x efficiency hole.
// Algorithm (R7-R9): k(i,j) = t_n^{i^2} * t_n^{j^2}, masked t=0 kills OOB
// taps (a=0 class only consumed at the output's own in-bounds column).
// Codegen rules: straight-line unrolls, constexpr indexing, packed f32 pairs.
__global__ __launch_bounds__(64) void gauss_psf_kernel(const float* __restrict__ image,
                                                       const float* __restrict__ psf,
                                                       float* __restrict__ out) {
    __shared__ float  tt[NHALO];        // masked t halo, 1.5 KB
    __shared__ float4 cp[6 * NSTRIP];   // class planes (ch0,ch1,ch2,w), 6 KB

    const int tid = threadIdx.x;            // 0..63
    const int bx0 = blockIdx.x * TW;
    const int by0 = blockIdx.y * TH;
    const int b   = blockIdx.z;

    const float* pw   = psf + (size_t)b * HH * WW;
    const float* img0 = image + (size_t)b * 3 * HH * WW;
    const float* img1 = img0 + HH * WW;
    const float* img2 = img0 + 2 * HH * WW;

    // ---- Phase 1: masked-t halo (384 px = exactly 6 passes of 64) ----
#pragma unroll
    for (int pass = 0; pass < 6; ++pass) {
        const int idx = pass * 64 + tid;
        const int row = idx >> 5, col = idx & 31;
        const int gy = by0 - RR + row, gx = bx0 - RR + col;
        const bool in = ((unsigned)gy < (unsigned)HH) && ((unsigned)gx < (unsigned)WW);
        const int cy = gy < 0 ? 0 : (gy > HH - 1 ? HH - 1 : gy);
        const int cx = gx < 0 ? 0 : (gx > WW - 1 ? WW - 1 : gx);
        const float w = pw[cy * WW + cx];
        const float a = -NLOG2E * __builtin_amdgcn_rcpf(fmaf(2.0f * w, w, EPS_F));
        tt[idx] = in ? __builtin_amdgcn_exp2f(a) : 0.0f;
    }
    __syncthreads();   // single-wave: no partner waves, ~free

    // ---- Pass V: 64 strip pixels = the whole wave ----
    {
        const int ly = tid >> 5;            // 0..1
        const int lx = tid & 31;            // 0..31
        const int gx = bx0 - RR + lx;
        const int gxc = gx < 0 ? 0 : (gx > WW - 1 ? WW - 1 : gx);
        const int gy = by0 + ly;

        f2 a0p[3], a1p[3], a2p[3], awp[3];  // class-pair accumulators
#pragma unroll
        for (int p = 0; p < 3; ++p) {
            a0p[p] = (f2)0.0f; a1p[p] = (f2)0.0f; a2p[p] = (f2)0.0f; awp[p] = (f2)0.0f;
        }

#pragma unroll
        for (int r = 0; r < KS; ++r) {
            const float t = tt[((ly + r) << 5) + lx];          // ds_read, const off
            int ry = gy + r - RR;
            ry = ry < 0 ? 0 : (ry > HH - 1 ? HH - 1 : ry);
            const int ni = ry * WW + gxc;
            const float i0 = img0[ni];
            const float i1 = img1[ni];
            const float i2 = img2[ni];

            const float t2 = t * t, t4 = t2 * t2, t8 = t4 * t4;
            const float t9 = t8 * t, t16 = t8 * t8, t25 = t16 * t9;

            const int ii = (r - RR) * (r - RR);                // constexpr after unroll
            const float u = ii == 0 ? 1.0f : ii == 1 ? t : ii == 4 ? t4
                          : ii == 9 ? t9 : ii == 16 ? t16 : t25;   // t^(i^2)

            const f2 u2  = {u, u};
            const f2 f01 = u2 * (f2){1.0f, t};                 // t^(i^2+{0,1})
            const f2 f23 = u2 * (f2){t4, t9};                  // t^(i^2+{4,9})
            const f2 f45 = u2 * (f2){t16, t25};                // t^(i^2+{16,25})

            const f2 i0v = {i0, i0}, i1v = {i1, i1}, i2v = {i2, i2};
            a0p[0] = fma2(i0v, f01, a0p[0]);
            a0p[1] = fma2(i0v, f23, a0p[1]);
            a0p[2] = fma2(i0v, f45, a0p[2]);
            a1p[0] = fma2(i1v, f01, a1p[0]);
            a1p[1] = fma2(i1v, f23, a1p[1]);
            a1p[2] = fma2(i1v, f45, a1p[2]);
            a2p[0] = fma2(i2v, f01, a2p[0]);
            a2p[1] = fma2(i2v, f23, a2p[1]);
            a2p[2] = fma2(i2v, f45, a2p[2]);
            awp[0] += f01;
            awp[1] += f23;
            awp[2] += f45;
        }

#pragma unroll
        for (int p = 0; p < 3; ++p) {                          // 6 x ds_write_b128
            cp[((2 * p) << 6) + tid]     = make_float4(a0p[p].x, a1p[p].x, a2p[p].x, awp[p].x);
            cp[((2 * p + 1) << 6) + tid] = make_float4(a0p[p].y, a1p[p].y, a2p[p].y, awp[p].y);
        }
    }
    __syncthreads();   // single-wave: ~free

    // ---- Pass H: 44 outputs among 64 lanes ----
    const int hy = tid >= TW ? 1 : 0;
    const int hx = tid - TW * hy;
    const int x  = bx0 + hx;
    if (tid < NOUT && x < WW) {
        const int hb = (hy << 5) + hx;      // strip index at j=0
        f2 s01 = (f2)0.0f, s2w = (f2)0.0f;
#pragma unroll
        for (int j = 0; j < KS; ++j) {
            const int jj = (j - RR) * (j - RR);                // constexpr
            const int ai = jj == 0 ? 0 : jj == 1 ? 1 : jj == 4 ? 2
                         : jj == 9 ? 3 : jj == 16 ? 4 : 5;
            const float4 v = cp[(ai << 6) + hb + j];           // ds_read_b128
            s01 += (f2){v.x, v.y};                             // pk_add
            s2w += (f2){v.z, v.w};
        }

        const float sw = s2w.y;                                // >= 1 (center tap)
        float inv = __builtin_amdgcn_rcpf(sw);
        inv = inv * (2.0f - sw * inv);                         // Newton: ~1e-7 rel
        const int y  = by0 + hy;
        const int oi = y * WW + x;
        float* outb = out + (size_t)b * 3 * HH * WW;
        outb[oi]               = s01.x * inv;
        outb[HH * WW + oi]     = s01.y * inv;
        outb[2 * HH * WW + oi] = s2w.x * inv;
    }
}

extern "C" void kernel_launch(void* const* d_in, const int* in_sizes, int n_in,
                              void* d_out, int out_size, void* d_ws, size_t ws_size,
                              hipStream_t stream) {
    const float* image = (const float*)d_in[0];
    const float* psf   = (const float*)d_in[1];
    float* out = (float*)d_out;

    dim3 block(64, 1, 1);                       // ONE wave per block
    dim3 grid((WW + TW - 1) / TW, HH / TH, 4);  // 24 x 256 x 4 = 24576 blocks
    gauss_psf_kernel<<<grid, block, 0, stream>>>(image, psf, out);
}

// Round 12
// 86.620 us; speedup vs baseline: 1.0928x; 1.0162x over previous
//
#include <hip/hip_runtime.h>

#define HH 512
#define WW 512
#define RR 5
#define KS 11
#define EPS_F 1e-5f
#define NLOG2E 1.44269504088896340736f
#define TW 64                 // output tile width
#define TH 4                  // output tile height
#define BY 5                  // 320 threads = 5 waves; pass V in one pass
#define SW (TW + 2 * RR)      // 74: strip width (x-halo)
#define SH (TH + 2 * RR)      // 14: t-tile height (y-halo)
#define NSTRIP (SW * TH)      // 296 strip pixels <= 320 threads

typedef float f2 __attribute__((ext_vector_type(2)));
__device__ __forceinline__ f2 fma2(f2 a, f2 b, f2 c) { return __builtin_elementwise_fma(a, b, c); }

// R12 = R9 (best: 85.5 us) with ONE change: pass-V loads batched into
// registers up front (11 ds_read + 33 global loads issued back-to-back, one
// wait), then a pure-VALU accumulate section. R11 falsified the barrier-convoy
// theory; remaining explanation for the 3x gap between summed pipe busy
// (~20 us) and kernel (~33 us) is per-row load->use latency exposure at only
// 5 waves/SIMD (LDS-limited occupancy). Staged arrays are constexpr-indexed
// after full unroll (R2 rule); peak live ~85 VGPR, no guarded multi-output
// inner loop (R3/R4 spill pattern avoided).
// Algorithm (R7-R9): k(i,j) = t_n^{i^2} * t_n^{j^2}; masked t=0 kills every
// OOB tap (a=0 class only consumed at the output's own in-bounds column).
__global__ __launch_bounds__(320) void gauss_psf_kernel(const float* __restrict__ image,
                                                        const float* __restrict__ psf,
                                                        float* __restrict__ out) {
    __shared__ float4 cp[6 * NSTRIP];   // class planes (ch0,ch1,ch2,w), 28.4 KB
    __shared__ float  tt[SH * SW];      // masked t tile, 4.1 KB

    const int tx  = threadIdx.x;            // 0..63
    const int ty  = threadIdx.y;            // 0..4
    const int tid = ty * 64 + tx;           // 0..319
    const int bx0 = blockIdx.x * TW;
    const int by0 = blockIdx.y * TH;
    const int b   = blockIdx.z;

    const float* pw   = psf + (size_t)b * HH * WW;
    const float* img0 = image + (size_t)b * 3 * HH * WW;
    const float* img1 = img0 + HH * WW;
    const float* img2 = img0 + 2 * HH * WW;

    // ---- Phase 1: masked-t tile (14 x 74 = 1036 values) ----
#pragma unroll
    for (int base = 0; base < SH * SW; base += 320) {
        const int idx = base + tid;
        if (idx < SH * SW) {
            const int row = idx / SW, col = idx - row * SW;
            const int gy = by0 - RR + row, gx = bx0 - RR + col;
            const bool in = ((unsigned)gy < (unsigned)HH) && ((unsigned)gx < (unsigned)WW);
            const int cy = gy < 0 ? 0 : (gy > HH - 1 ? HH - 1 : gy);
            const int cx = gx < 0 ? 0 : (gx > WW - 1 ? WW - 1 : gx);
            const float w = pw[cy * WW + cx];
            const float a = -NLOG2E * __builtin_amdgcn_rcpf(fmaf(2.0f * w, w, EPS_F));
            tt[idx] = in ? __builtin_amdgcn_exp2f(a) : 0.0f;
        }
    }
    __syncthreads();

    // ---- Pass V: 296 strip pixels, one per thread ----
    if (tid < NSTRIP) {
        const int ly = tid / SW;            // 0..3
        const int lx = tid - ly * SW;       // 0..73
        const int gx = bx0 - RR + lx;
        const int gxc = gx < 0 ? 0 : (gx > WW - 1 ? WW - 1 : gx);
        const int gy = by0 + ly;

        // ---- Stage ALL loads first (issued back-to-back, single wait) ----
        float tv[KS];
#pragma unroll
        for (int r = 0; r < KS; ++r)
            tv[r] = tt[(ly + r) * SW + lx];                    // 11 ds_read b32

        float iv0[KS], iv1[KS], iv2[KS];
#pragma unroll
        for (int r = 0; r < KS; ++r) {
            int ry = gy + r - RR;
            ry = ry < 0 ? 0 : (ry > HH - 1 ? HH - 1 : ry);
            const int ni = ry * WW + gxc;
            iv0[r] = img0[ni];                                 // 33 global loads
            iv1[r] = img1[ni];
            iv2[r] = img2[ni];
        }

        // ---- Pure-VALU accumulate ----
        f2 a0p[3], a1p[3], a2p[3], awp[3];  // class-pair accumulators
#pragma unroll
        for (int p = 0; p < 3; ++p) {
            a0p[p] = (f2)0.0f; a1p[p] = (f2)0.0f; a2p[p] = (f2)0.0f; awp[p] = (f2)0.0f;
        }

#pragma unroll
        for (int r = 0; r < KS; ++r) {
            const float t = tv[r];
            const float t2 = t * t, t4 = t2 * t2, t8 = t4 * t4;
            const float t9 = t8 * t, t16 = t8 * t8, t25 = t16 * t9;

            const int ii = (r - RR) * (r - RR);                // constexpr after unroll
            const float u = ii == 0 ? 1.0f : ii == 1 ? t : ii == 4 ? t4
                          : ii == 9 ? t9 : ii == 16 ? t16 : t25;   // t^(i^2)

            const f2 u2  = {u, u};
            const f2 f01 = u2 * (f2){1.0f, t};                 // t^(i^2+{0,1})
            const f2 f23 = u2 * (f2){t4, t9};                  // t^(i^2+{4,9})
            const f2 f45 = u2 * (f2){t16, t25};                // t^(i^2+{16,25})

            const f2 i0v = {iv0[r], iv0[r]}, i1v = {iv1[r], iv1[r]}, i2v = {iv2[r], iv2[r]};
            a0p[0] = fma2(i0v, f01, a0p[0]);
            a0p[1] = fma2(i0v, f23, a0p[1]);
            a0p[2] = fma2(i0v, f45, a0p[2]);
            a1p[0] = fma2(i1v, f01, a1p[0]);
            a1p[1] = fma2(i1v, f23, a1p[1]);
            a1p[2] = fma2(i1v, f45, a1p[2]);
            a2p[0] = fma2(i2v, f01, a2p[0]);
            a2p[1] = fma2(i2v, f23, a2p[1]);
            a2p[2] = fma2(i2v, f45, a2p[2]);
            awp[0] += f01;
            awp[1] += f23;
            awp[2] += f45;
        }

#pragma unroll
        for (int p = 0; p < 3; ++p) {                          // 6 x ds_write_b128
            cp[(2 * p) * NSTRIP + tid]     = make_float4(a0p[p].x, a1p[p].x, a2p[p].x, awp[p].x);
            cp[(2 * p + 1) * NSTRIP + tid] = make_float4(a0p[p].y, a1p[p].y, a2p[p].y, awp[p].y);
        }
    }
    __syncthreads();

    // ---- Pass H: 256 output pixels (waves 0-3); wave 4 exits uniformly ----
    if (tid < TW * TH) {
        const int hx = tid & 63, hy = tid >> 6;
        const int hb = hy * SW + hx;        // strip index of (y, x-RR+j) at j=0
        f2 s01 = (f2)0.0f, s2w = (f2)0.0f;
#pragma unroll
        for (int j = 0; j < KS; ++j) {
            const int jj = (j - RR) * (j - RR);                // constexpr
            const int ai = jj == 0 ? 0 : jj == 1 ? 1 : jj == 4 ? 2
                         : jj == 9 ? 3 : jj == 16 ? 4 : 5;
            const float4 v = cp[ai * NSTRIP + hb + j];         // ds_read_b128
            s01 += (f2){v.x, v.y};                             // pk_add
            s2w += (f2){v.z, v.w};
        }

        const float sw = s2w.y;                                // >= 1 (center tap)
        float inv = __builtin_amdgcn_rcpf(sw);
        inv = inv * (2.0f - sw * inv);                         // Newton: ~1e-7 rel
        const int x = bx0 + hx, y = by0 + hy;
        const int oi = y * WW + x;
        float* outb = out + (size_t)b * 3 * HH * WW;
        outb[oi]               = s01.x * inv;
        outb[HH * WW + oi]     = s01.y * inv;
        outb[2 * HH * WW + oi] = s2w.x * inv;
    }
}

extern "C" void kernel_launch(void* const* d_in, const int* in_sizes, int n_in,
                              void* d_out, int out_size, void* d_ws, size_t ws_size,
                              hipStream_t stream) {
    const float* image = (const float*)d_in[0];
    const float* psf   = (const float*)d_in[1];
    float* out = (float*)d_out;

    dim3 block(TW, BY, 1);                 // 320 threads = 5 waves
    dim3 grid(WW / TW, HH / TH, 4);        // 8 x 128 x 4 = 4096 blocks
    gauss_psf_kernel<<<grid, block, 0, stream>>>(image, psf, out);
}